// Round 7
// baseline (748.771 us; speedup 1.0000x reference)
//
#include <hip/hip_runtime.h>
#include <float.h>
#include <math.h>

#define N_PTS 8192
#define NB    256         // blocks (1 per CU)
#define NT    512         // 8 waves/block -> 2 waves/SIMD
#define QPB   32          // queries per block
#define QPT   8           // queries per thread
#define RC    64          // candidates per range
#define STEPS 11          // STEPLIM + 1
#define TOLV  1e-4

#define PADSLOT(i) ((i) + ((i) >> 6))
#define SC_SZ (N_PTS + N_PTS/64)   // 8320 float4 slots = 133120 B

#define FXSCALE   68719476736.0    // 2^36 fixed-point scale (deterministic sums)
#define INVFX     (1.0 / 68719476736.0)

// ---- ws layout (bytes) ----
#define WS_P2F    0         // float4[8192]    = 131072
#define WS_TEMPPC 131072    // float [24576]   -> 229376
#define WS_ACC    229376    // ll[16] + u32 ticket (136 B, memset each call)
#define WS_GS     229760    // GS state

struct GS { float Rt[12]; double err; int done; int pad; };

// ===========================================================================
// Kabsch via Jacobi eigendecomposition of H^T H — FLOAT (reference SVD is f32).
// ===========================================================================
__device__ void kabsch3f(const float H[3][3], const float c1[3], const float c2[3],
                         float R[3][3], float t[3]) {
    float A[3][3];
    for (int i = 0; i < 3; ++i)
        for (int j = 0; j < 3; ++j) {
            float sacc = 0.0f;
            for (int k = 0; k < 3; ++k) sacc += H[k][i] * H[k][j];
            A[i][j] = sacc;
        }
    float V[3][3] = {{1,0,0},{0,1,0},{0,0,1}};
    for (int sweep = 0; sweep < 6; ++sweep) {
        const int PQ[3][2] = {{0,1},{0,2},{1,2}};
        for (int mm = 0; mm < 3; ++mm) {
            int p = PQ[mm][0], q = PQ[mm][1];
            float apq = A[p][q];
            if (fabsf(apq) < 1e-30f) continue;
            float app = A[p][p], aqq = A[q][q];
            float tau = (aqq - app) / (2.0f * apq);
            float tt = (tau >= 0.0f) ? 1.0f / (tau + sqrtf(1.0f + tau*tau))
                                     : 1.0f / (tau - sqrtf(1.0f + tau*tau));
            float c = 1.0f / sqrtf(1.0f + tt*tt), s = tt * c;
            A[p][p] = app - tt * apq;
            A[q][q] = aqq + tt * apq;
            A[p][q] = 0.0f; A[q][p] = 0.0f;
            int k = 3 - p - q;
            float akp = A[k][p], akq = A[k][q];
            A[k][p] = c*akp - s*akq; A[p][k] = A[k][p];
            A[k][q] = s*akp + c*akq; A[q][k] = A[k][q];
            for (int r = 0; r < 3; ++r) {
                float vp = V[r][p], vq = V[r][q];
                V[r][p] = c*vp - s*vq;
                V[r][q] = s*vp + c*vq;
            }
        }
    }
    float lam[3] = {A[0][0], A[1][1], A[2][2]};
    int ord[3] = {0,1,2};
    for (int i = 0; i < 2; ++i)
        for (int j = i+1; j < 3; ++j)
            if (lam[ord[j]] > lam[ord[i]]) { int tmp = ord[i]; ord[i] = ord[j]; ord[j] = tmp; }
    float v0[3] = {V[0][ord[0]], V[1][ord[0]], V[2][ord[0]]};
    float v1[3] = {V[0][ord[1]], V[1][ord[1]], V[2][ord[1]]};
    float v2[3] = {V[0][ord[2]], V[1][ord[2]], V[2][ord[2]]};

    float u0[3], u1[3], hv2[3];
    for (int i = 0; i < 3; ++i) u0[i] = H[i][0]*v0[0] + H[i][1]*v0[1] + H[i][2]*v0[2];
    float n0 = sqrtf(u0[0]*u0[0] + u0[1]*u0[1] + u0[2]*u0[2]);
    n0 = fmaxf(n0, 1e-30f);
    for (int i = 0; i < 3; ++i) u0[i] /= n0;

    for (int i = 0; i < 3; ++i) u1[i] = H[i][0]*v1[0] + H[i][1]*v1[1] + H[i][2]*v1[2];
    float d01 = u1[0]*u0[0] + u1[1]*u0[1] + u1[2]*u0[2];
    for (int i = 0; i < 3; ++i) u1[i] -= d01 * u0[i];
    float n1 = sqrtf(u1[0]*u1[0] + u1[1]*u1[1] + u1[2]*u1[2]);
    n1 = fmaxf(n1, 1e-30f);
    for (int i = 0; i < 3; ++i) u1[i] /= n1;

    float u2[3] = {u0[1]*u1[2] - u0[2]*u1[1],
                   u0[2]*u1[0] - u0[0]*u1[2],
                   u0[0]*u1[1] - u0[1]*u1[0]};
    for (int i = 0; i < 3; ++i) hv2[i] = H[i][0]*v2[0] + H[i][1]*v2[1] + H[i][2]*v2[2];
    if (hv2[0]*u2[0] + hv2[1]*u2[1] + hv2[2]*u2[2] < 0.0f) {
        v2[0] = -v2[0]; v2[1] = -v2[1]; v2[2] = -v2[2];
    }
    float cx = v1[1]*v2[2] - v1[2]*v2[1];
    float cy = v1[2]*v2[0] - v1[0]*v2[2];
    float cz = v1[0]*v2[1] - v1[1]*v2[0];
    float detV = v0[0]*cx + v0[1]*cy + v0[2]*cz;
    float dsg = (detV < 0.0f) ? -1.0f : 1.0f;

    for (int i = 0; i < 3; ++i)
        for (int j = 0; j < 3; ++j)
            R[i][j] = v0[i]*u0[j] + v1[i]*u1[j] + dsg * v2[i]*u2[j];
    for (int i = 0; i < 3; ++i)
        t[i] = c2[i] - (R[i][0]*c1[0] + R[i][1]*c1[1] + R[i][2]*c1[2]);
}

// Build centroids + H (double sums -> float outputs).
__device__ __forceinline__ void build_Hf(const double s[16], float c1[3], float c2[3],
                                         float H[3][3]) {
    const double Nn = (double)N_PTS;
    double c1d[3] = {s[1]/Nn, s[2]/Nn, s[3]/Nn};
    double c2d[3] = {s[4]/Nn, s[5]/Nn, s[6]/Nn};
    for (int i = 0; i < 3; ++i) { c1[i] = (float)c1d[i]; c2[i] = (float)c2d[i]; }
    for (int i = 0; i < 3; ++i)
        for (int j = 0; j < 3; ++j)
            H[i][j] = (float)(s[7 + 3*i + j] - Nn * c1d[i] * c2d[j]);
}

// identical fma chain in scan & rescan -> exact float equality in recovery
__device__ __forceinline__ float dist_val(float4 s, float mx, float my, float mz) {
    float v = fmaf(mx, s.x, s.w);
    v = fmaf(my, s.y, v);
    v = fmaf(mz, s.z, v);
    return v;
}

// ===========================================================================
// One ICP iteration per dispatch (it = 0..STEPS).
//   it<STEPS : transform (R,t from gs) + NN scan + fixed-point atomic reduce;
//              ticket-winner block computes gate + Kabsch -> gs.
//   it==STEPS: transform + final-fit partials; winner computes final Kabsch -> out.
// ===========================================================================
__global__ __launch_bounds__(NT, 2) void icp_step(
    const float* __restrict__ p1, const float* __restrict__ p2,
    float4* __restrict__ p2f, float* __restrict__ temppc,
    GS* __restrict__ gs, unsigned long long* __restrict__ acc,
    unsigned int* __restrict__ ticket, float* __restrict__ out, int it)
{
    __shared__ float4 sCand[SC_SZ];      // 133120 B
    __shared__ float4 sQ[QPB];
    __shared__ float  sWmin[8][QPT];
    __shared__ int    sWin[QPB];
    __shared__ float  sRt[12];
    const int tid = threadIdx.x, bid = blockIdx.x;

    const int done_prev = (it > 0) ? gs->done : 0;
    const bool scanning = (it < STEPS);
    if (scanning && done_prev) return;   // frozen: nothing changes this iter

    // ---- stage all 8192 candidates into LDS (bank-padded) ----
    if (scanning) {
        if (it == 0) {
            #pragma unroll
            for (int k = 0; k < 16; ++k) {
                int i = tid + NT*k;
                float x = p2[3*i], y = p2[3*i+1], z = p2[3*i+2];
                sCand[PADSLOT(i)] = make_float4(x, y, z, x*x + y*y + z*z);
            }
        } else {
            #pragma unroll
            for (int k = 0; k < 16; ++k) {
                int i = tid + NT*k;
                sCand[PADSLOT(i)] = p2f[i];
            }
        }
    }
    if (it > 0 && !done_prev && tid < 12) sRt[tid] = gs->Rt[tid];
    if (tid < QPB) sWin[tid] = 0x7fffffff;
    __syncthreads();

    if (it == 0 && tid < QPB) {          // publish packed candidates once
        int i = bid*QPB + tid;
        p2f[i] = sCand[PADSLOT(i)];
    }

    // ---- own query coords: load, (transform), store, share ----
    if (tid < QPB) {
        int q = bid*QPB + tid;
        float x, y, z;
        if (it == 0) {
            x = p1[3*q]; y = p1[3*q+1]; z = p1[3*q+2];
            temppc[3*q] = x; temppc[3*q+1] = y; temppc[3*q+2] = z;
        } else {
            x = temppc[3*q]; y = temppc[3*q+1]; z = temppc[3*q+2];
            if (!done_prev) {
                float nx = fmaf(sRt[0], x, fmaf(sRt[1], y, fmaf(sRt[2], z, sRt[9])));
                float ny = fmaf(sRt[3], x, fmaf(sRt[4], y, fmaf(sRt[5], z, sRt[10])));
                float nz = fmaf(sRt[6], x, fmaf(sRt[7], y, fmaf(sRt[8], z, sRt[11])));
                x = nx; y = ny; z = nz;
                temppc[3*q] = x; temppc[3*q+1] = y; temppc[3*q+2] = z;
            }
        }
        sQ[tid] = make_float4(x, y, z, x*x + y*y + z*z);
    }
    __syncthreads();

    double vals[16];

    if (scanning) {
        // ---- NN scan: group g (8 queries) x range r (64 candidates), value-only ----
        const int g = tid >> 7;        // 0..3
        const int r = tid & 127;       // 0..127 (global cands 64r..64r+63)
        float qx[QPT], qy[QPT], qz[QPT];
        #pragma unroll
        for (int k = 0; k < QPT; ++k) {
            float4 a = sQ[QPT*g + k];
            qx[k] = -2.f*a.x; qy[k] = -2.f*a.y; qz[k] = -2.f*a.z;
        }
        float tmin[QPT];
        #pragma unroll
        for (int k = 0; k < QPT; ++k) tmin[k] = FLT_MAX;

        const int sb = 65*r;           // PADSLOT(64*r): contiguous 64 slots
        float4 cur = sCand[sb];
        #pragma unroll 4
        for (int j = 0; j < RC - 1; ++j) {
            float4 nxt = sCand[sb + j + 1];
            #pragma unroll
            for (int k = 0; k < QPT; ++k)
                tmin[k] = fminf(tmin[k], dist_val(cur, qx[k], qy[k], qz[k]));
            cur = nxt;
        }
        #pragma unroll
        for (int k = 0; k < QPT; ++k)
            tmin[k] = fminf(tmin[k], dist_val(cur, qx[k], qy[k], qz[k]));

        float omin[QPT];               // per-range minima (pre-butterfly)
        #pragma unroll
        for (int k = 0; k < QPT; ++k) omin[k] = tmin[k];

        #pragma unroll
        for (int off = 1; off < 64; off <<= 1) {
            #pragma unroll
            for (int k = 0; k < QPT; ++k)
                tmin[k] = fminf(tmin[k], __shfl_xor(tmin[k], off, 64));
        }
        const int w = tid >> 6;
        if ((tid & 63) == 0) {
            #pragma unroll
            for (int k = 0; k < QPT; ++k) sWmin[w][k] = tmin[k];
        }
        __syncthreads();

        // winner range per query: smallest r achieving the global min
        #pragma unroll
        for (int k = 0; k < QPT; ++k) {
            float gm = fminf(sWmin[2*g][k], sWmin[2*g+1][k]);
            if (omin[k] == gm) atomicMin(&sWin[QPT*g + k], r);
        }
        __syncthreads();

        // ---- per-query finisher (tid<32): rescan winning range for first index ----
        if (tid < 64) {
            if (tid < 32) {
                int q = tid, g2 = q >> 3, k2 = q & 7;
                float gm = fminf(sWmin[2*g2][k2], sWmin[2*g2+1][k2]);
                int rw = sWin[q];
                float4 a4 = sQ[q];
                float mx = -2.f*a4.x, my = -2.f*a4.y, mz = -2.f*a4.z;
                int bix = -1;
                const int sbw = 65*rw;
                #pragma unroll 8
                for (int j = 0; j < RC; ++j) {
                    float v = dist_val(sCand[sbw + j], mx, my, mz);
                    if (v == gm && bix < 0) bix = RC*rw + j;
                }
                float d2 = fmaxf(gm + a4.w, 0.0f);
                float dmin = sqrtf(d2);
                float4 b4 = sCand[PADSLOT(bix)];
                vals[0] = (double)dmin;
                vals[1] = (double)a4.x; vals[2] = (double)a4.y; vals[3] = (double)a4.z;
                vals[4] = (double)b4.x; vals[5] = (double)b4.y; vals[6] = (double)b4.z;
                vals[7]  = (double)a4.x*b4.x; vals[8]  = (double)a4.x*b4.y; vals[9]  = (double)a4.x*b4.z;
                vals[10] = (double)a4.y*b4.x; vals[11] = (double)a4.y*b4.y; vals[12] = (double)a4.y*b4.z;
                vals[13] = (double)a4.z*b4.x; vals[14] = (double)a4.z*b4.y; vals[15] = (double)a4.z*b4.z;
            } else {
                #pragma unroll
                for (int k = 0; k < 16; ++k) vals[k] = 0.0;
            }
        }
    } else {
        // ---- final-fit partials (a = p1, b = final coords) ----
        if (tid < 64) {
            if (tid < 32) {
                int q = bid*QPB + tid;
                float ax = p1[3*q], ay = p1[3*q+1], az = p1[3*q+2];
                float4 b4 = sQ[tid];
                vals[0] = 0.0;
                vals[1] = (double)ax;   vals[2] = (double)ay;   vals[3] = (double)az;
                vals[4] = (double)b4.x; vals[5] = (double)b4.y; vals[6] = (double)b4.z;
                vals[7]  = (double)ax*b4.x; vals[8]  = (double)ax*b4.y; vals[9]  = (double)ax*b4.z;
                vals[10] = (double)ay*b4.x; vals[11] = (double)ay*b4.y; vals[12] = (double)ay*b4.z;
                vals[13] = (double)az*b4.x; vals[14] = (double)az*b4.y; vals[15] = (double)az*b4.z;
            } else {
                #pragma unroll
                for (int k = 0; k < 16; ++k) vals[k] = 0.0;
            }
        }
    }

    // ---- block reduce (same order as r6: 5-step xor over 32 lanes) + atomics ----
    if (tid < 64) {
        #pragma unroll
        for (int off = 1; off < 32; off <<= 1) {
            #pragma unroll
            for (int k = 0; k < 16; ++k) vals[k] += __shfl_xor(vals[k], off, 64);
        }
        if (tid == 0) {
            #pragma unroll
            for (int k = 0; k < 16; ++k) {
                long long fx = __double2ll_rn(vals[k] * FXSCALE);
                atomicAdd(&acc[k], (unsigned long long)fx);
            }
            __threadfence();
            unsigned int old = atomicAdd(ticket, 1u);
            if (old == NB - 1) {
                // ---- winner epilogue: exact global sums -> gate (+ Kabsch) ----
                double sv[16];
                #pragma unroll
                for (int k = 0; k < 16; ++k) {
                    unsigned long long u = atomicAdd(&acc[k], 0ULL);
                    sv[k] = (double)(long long)u * INVFX;
                    atomicExch(&acc[k], 0ULL);
                }
                atomicExch(ticket, 0u);
                if (scanning) {
                    double errnew = sv[0] / (double)N_PTS;
                    double err = (it == 0) ? __builtin_inf() : gs->err;
                    double rel = fabs((errnew - err) / err);   // nan first iter -> false
                    int nd = (rel < TOLV) ? 1 : 0;
                    gs->done = nd;
                    gs->err  = nd ? err : errnew;
                    if (!nd) {
                        float c1[3], c2[3], H[3][3], Rm[3][3], tv[3];
                        build_Hf(sv, c1, c2, H);
                        kabsch3f(H, c1, c2, Rm, tv);
                        #pragma unroll
                        for (int i = 0; i < 3; ++i) {
                            gs->Rt[3*i]   = Rm[i][0];
                            gs->Rt[3*i+1] = Rm[i][1];
                            gs->Rt[3*i+2] = Rm[i][2];
                            gs->Rt[9+i]   = tv[i];
                        }
                    }
                } else {
                    float c1[3], c2[3], H[3][3], Rm[3][3], tv[3];
                    build_Hf(sv, c1, c2, H);
                    kabsch3f(H, c1, c2, Rm, tv);
                    #pragma unroll
                    for (int i = 0; i < 3; ++i) {
                        out[4*i + 0] = Rm[i][0];
                        out[4*i + 1] = Rm[i][1];
                        out[4*i + 2] = Rm[i][2];
                        out[4*i + 3] = tv[i];
                    }
                }
            }
        }
    }
}

// ===========================================================================
extern "C" void kernel_launch(void* const* d_in, const int* in_sizes, int n_in,
                              void* d_out, int out_size, void* d_ws, size_t ws_size,
                              hipStream_t stream) {
    const float* p1 = (const float*)d_in[0];
    const float* p2 = (const float*)d_in[1];
    float* out = (float*)d_out;
    char* ws = (char*)d_ws;

    float4*             p2f    = (float4*)(ws + WS_P2F);
    float*              temppc = (float*) (ws + WS_TEMPPC);
    unsigned long long* acc    = (unsigned long long*)(ws + WS_ACC);
    unsigned int*       ticket = (unsigned int*)(ws + WS_ACC + 16*8);
    GS*                 gs     = (GS*)    (ws + WS_GS);

    hipMemsetAsync(ws + WS_ACC, 0, 17*8, stream);   // acc + ticket zero each call
    for (int it = 0; it <= STEPS; ++it) {
        icp_step<<<NB, NT, 0, stream>>>(p1, p2, p2f, temppc, gs, acc, ticket, out, it);
    }
}

// Round 8
// 421.931 us; speedup vs baseline: 1.7746x; 1.7746x over previous
//
#include <hip/hip_runtime.h>
#include <float.h>
#include <math.h>

#define N_PTS 8192
#define NB    256         // blocks (1 per CU)
#define NT    512         // 8 waves/block
#define QPB   32          // queries per block
#define QPT   8           // queries per thread group
#define RC    64          // candidates per range
#define NITER 11          // STEPLIM + 1 NN/gate iterations
#define TOLV  1e-4

#define PADSLOT(i) ((i) + ((i) >> 6))
#define SC_SZ (N_PTS + N_PTS/64)   // 8320 float4 slots = 133120 B

#define AGENT __HIP_MEMORY_SCOPE_AGENT

// ---- ws layout (bytes) ----
#define WS_BP     0          // ull[2][NB][16]  = 65536
#define WS_FLAGS  65536      // u32[NB]         -> 66560
// fallback arrays (only used if cooperative launch fails)
#define WS_P2F    131072     // float4[8192]    -> 262144
#define WS_TEMPPC 262144     // float[24576]    -> 360448
#define WS_FBA    360448     // double[256*16]  -> 393216
#define WS_FBB    393216     // double[256*16]  -> 425984
#define WS_ERRH   425984     // double[16]      -> 426112
#define WS_DONEH  426112     // int[16]

// ===========================================================================
// f32 Kabsch via Jacobi eigendecomposition of H^T H (reference SVD is f32).
// ===========================================================================
__device__ void kabsch3f(const float H[3][3], const float c1[3], const float c2[3],
                         float R[3][3], float t[3]) {
    float A[3][3];
    for (int i = 0; i < 3; ++i)
        for (int j = 0; j < 3; ++j) {
            float sacc = 0.0f;
            for (int k = 0; k < 3; ++k) sacc += H[k][i] * H[k][j];
            A[i][j] = sacc;
        }
    float V[3][3] = {{1,0,0},{0,1,0},{0,0,1}};
    for (int sweep = 0; sweep < 6; ++sweep) {
        const int PQ[3][2] = {{0,1},{0,2},{1,2}};
        for (int mm = 0; mm < 3; ++mm) {
            int p = PQ[mm][0], q = PQ[mm][1];
            float apq = A[p][q];
            if (fabsf(apq) < 1e-30f) continue;
            float app = A[p][p], aqq = A[q][q];
            float tau = (aqq - app) / (2.0f * apq);
            float tt = (tau >= 0.0f) ? 1.0f / (tau + sqrtf(1.0f + tau*tau))
                                     : 1.0f / (tau - sqrtf(1.0f + tau*tau));
            float c = 1.0f / sqrtf(1.0f + tt*tt), s = tt * c;
            A[p][p] = app - tt * apq;
            A[q][q] = aqq + tt * apq;
            A[p][q] = 0.0f; A[q][p] = 0.0f;
            int k = 3 - p - q;
            float akp = A[k][p], akq = A[k][q];
            A[k][p] = c*akp - s*akq; A[p][k] = A[k][p];
            A[k][q] = s*akp + c*akq; A[q][k] = A[k][q];
            for (int r = 0; r < 3; ++r) {
                float vp = V[r][p], vq = V[r][q];
                V[r][p] = c*vp - s*vq;
                V[r][q] = s*vp + c*vq;
            }
        }
    }
    float lam[3] = {A[0][0], A[1][1], A[2][2]};
    int ord[3] = {0,1,2};
    for (int i = 0; i < 2; ++i)
        for (int j = i+1; j < 3; ++j)
            if (lam[ord[j]] > lam[ord[i]]) { int tmp = ord[i]; ord[i] = ord[j]; ord[j] = tmp; }
    float v0[3] = {V[0][ord[0]], V[1][ord[0]], V[2][ord[0]]};
    float v1[3] = {V[0][ord[1]], V[1][ord[1]], V[2][ord[1]]};
    float v2[3] = {V[0][ord[2]], V[1][ord[2]], V[2][ord[2]]};

    float u0[3], u1[3], hv2[3];
    for (int i = 0; i < 3; ++i) u0[i] = H[i][0]*v0[0] + H[i][1]*v0[1] + H[i][2]*v0[2];
    float n0 = sqrtf(u0[0]*u0[0] + u0[1]*u0[1] + u0[2]*u0[2]);
    n0 = fmaxf(n0, 1e-30f);
    for (int i = 0; i < 3; ++i) u0[i] /= n0;

    for (int i = 0; i < 3; ++i) u1[i] = H[i][0]*v1[0] + H[i][1]*v1[1] + H[i][2]*v1[2];
    float d01 = u1[0]*u0[0] + u1[1]*u0[1] + u1[2]*u0[2];
    for (int i = 0; i < 3; ++i) u1[i] -= d01 * u0[i];
    float n1 = sqrtf(u1[0]*u1[0] + u1[1]*u1[1] + u1[2]*u1[2]);
    n1 = fmaxf(n1, 1e-30f);
    for (int i = 0; i < 3; ++i) u1[i] /= n1;

    float u2[3] = {u0[1]*u1[2] - u0[2]*u1[1],
                   u0[2]*u1[0] - u0[0]*u1[2],
                   u0[0]*u1[1] - u0[1]*u1[0]};
    for (int i = 0; i < 3; ++i) hv2[i] = H[i][0]*v2[0] + H[i][1]*v2[1] + H[i][2]*v2[2];
    if (hv2[0]*u2[0] + hv2[1]*u2[1] + hv2[2]*u2[2] < 0.0f) {
        v2[0] = -v2[0]; v2[1] = -v2[1]; v2[2] = -v2[2];
    }
    float cx = v1[1]*v2[2] - v1[2]*v2[1];
    float cy = v1[2]*v2[0] - v1[0]*v2[2];
    float cz = v1[0]*v2[1] - v1[1]*v2[0];
    float detV = v0[0]*cx + v0[1]*cy + v0[2]*cz;
    float dsg = (detV < 0.0f) ? -1.0f : 1.0f;

    for (int i = 0; i < 3; ++i)
        for (int j = 0; j < 3; ++j)
            R[i][j] = v0[i]*u0[j] + v1[i]*u1[j] + dsg * v2[i]*u2[j];
    for (int i = 0; i < 3; ++i)
        t[i] = c2[i] - (R[i][0]*c1[0] + R[i][1]*c1[1] + R[i][2]*c1[2]);
}

__device__ __forceinline__ void build_Hf(const double s[16], float c1[3], float c2[3],
                                         float H[3][3]) {
    const double Nn = (double)N_PTS;
    double c1d[3] = {s[1]/Nn, s[2]/Nn, s[3]/Nn};
    double c2d[3] = {s[4]/Nn, s[5]/Nn, s[6]/Nn};
    for (int i = 0; i < 3; ++i) { c1[i] = (float)c1d[i]; c2[i] = (float)c2d[i]; }
    for (int i = 0; i < 3; ++i)
        for (int j = 0; j < 3; ++j)
            H[i][j] = (float)(s[7 + 3*i + j] - Nn * c1d[i] * c2d[j]);
}

__device__ __forceinline__ float dist_val(float4 s, float mx, float my, float mz) {
    float v = fmaf(mx, s.x, s.w);
    v = fmaf(my, s.y, v);
    v = fmaf(mz, s.z, v);
    return v;
}

__device__ __forceinline__ void bp_store(unsigned long long* p, double v) {
    __hip_atomic_store(p, (unsigned long long)__double_as_longlong(v),
                       __ATOMIC_RELAXED, AGENT);
}
__device__ __forceinline__ double bp_load(const unsigned long long* p) {
    unsigned long long u = __hip_atomic_load(p, __ATOMIC_RELAXED, AGENT);
    return __longlong_as_double((long long)u);
}

// ===========================================================================
// PERSISTENT kernel: whole ICP in one dispatch, hand-rolled flag sync
// (no grid.sync). Candidates staged in LDS ONCE; queries live in LDS.
// Every block redundantly reduces all partials (fixed order -> deterministic)
// and computes gate + Kabsch locally -> no aggregator round-trip, no
// contended atomics (flags/partials are distinct addresses).
// ===========================================================================
__global__ __launch_bounds__(NT) void icp_persist(
    const float* __restrict__ p1, const float* __restrict__ p2,
    unsigned long long* __restrict__ bp,     // [2][NB][16]
    unsigned int* __restrict__ flags,        // [NB], zeroed per call
    float* __restrict__ out)
{
    __shared__ float4 sCand[SC_SZ];      // 133120 B, persists whole run
    __shared__ float4 sQ[QPB];
    __shared__ float  sWmin[8][QPT];
    __shared__ int    sWin[QPB];
    __shared__ float  sRt[12];
    __shared__ int    sDone;
    const int tid = threadIdx.x, bid = blockIdx.x;

    // ---- one-time staging: all 8192 candidates (|s|^2 in w) ----
    #pragma unroll
    for (int k = 0; k < 16; ++k) {
        int i = tid + NT*k;
        float x = p2[3*i], y = p2[3*i+1], z = p2[3*i+2];
        sCand[PADSLOT(i)] = make_float4(x, y, z, x*x + y*y + z*z);
    }
    if (tid < QPB) {
        int q = bid*QPB + tid;
        float x = p1[3*q], y = p1[3*q+1], z = p1[3*q+2];
        sQ[tid] = make_float4(x, y, z, x*x + y*y + z*z);
    }

    double err_loc = __builtin_inf();    // meaningful on tid 0 (identical in all blocks)
    int rnd = 0;

    for (int it = 0; it < NITER; ++it) {
        if (tid < QPB) sWin[tid] = 0x7fffffff;
        __syncthreads();                 // staging/sQ/sWin visible

        // ---- NN scan: group g (8 queries) x range r (64 cands), value-only ----
        const int g = tid >> 7;          // 0..3
        const int r = tid & 127;         // 0..127
        float qx[QPT], qy[QPT], qz[QPT];
        #pragma unroll
        for (int k = 0; k < QPT; ++k) {
            float4 a = sQ[QPT*g + k];
            qx[k] = -2.f*a.x; qy[k] = -2.f*a.y; qz[k] = -2.f*a.z;
        }
        float tmin[QPT];
        #pragma unroll
        for (int k = 0; k < QPT; ++k) tmin[k] = FLT_MAX;
        const int sb = 65*r;             // PADSLOT(64*r): contiguous 64 slots
        float4 cur = sCand[sb];
        #pragma unroll 4
        for (int j = 0; j < RC - 1; ++j) {
            float4 nxt = sCand[sb + j + 1];
            #pragma unroll
            for (int k = 0; k < QPT; ++k)
                tmin[k] = fminf(tmin[k], dist_val(cur, qx[k], qy[k], qz[k]));
            cur = nxt;
        }
        #pragma unroll
        for (int k = 0; k < QPT; ++k)
            tmin[k] = fminf(tmin[k], dist_val(cur, qx[k], qy[k], qz[k]));

        float omin[QPT];
        #pragma unroll
        for (int k = 0; k < QPT; ++k) omin[k] = tmin[k];
        #pragma unroll
        for (int off = 1; off < 64; off <<= 1) {
            #pragma unroll
            for (int k = 0; k < QPT; ++k)
                tmin[k] = fminf(tmin[k], __shfl_xor(tmin[k], off, 64));
        }
        const int w = tid >> 6;
        if ((tid & 63) == 0) {
            #pragma unroll
            for (int k = 0; k < QPT; ++k) sWmin[w][k] = tmin[k];
        }
        __syncthreads();

        #pragma unroll
        for (int k = 0; k < QPT; ++k) {
            float gm = fminf(sWmin[2*g][k], sWmin[2*g+1][k]);
            if (omin[k] == gm) atomicMin(&sWin[QPT*g + k], r);
        }
        __syncthreads();

        // ---- finisher + per-block partials + publish ----
        ++rnd;
        const int par = rnd & 1;
        if (tid < 64) {
            double vals[16];
            if (tid < 32) {
                int q = tid, g2 = q >> 3, k2 = q & 7;
                float gm = fminf(sWmin[2*g2][k2], sWmin[2*g2+1][k2]);
                int rw = sWin[q];
                float4 a4 = sQ[q];
                float mx = -2.f*a4.x, my = -2.f*a4.y, mz = -2.f*a4.z;
                int bix = -1;
                const int sbw = 65*rw;
                #pragma unroll 8
                for (int j = 0; j < RC; ++j) {
                    float v = dist_val(sCand[sbw + j], mx, my, mz);
                    if (v == gm && bix < 0) bix = RC*rw + j;
                }
                float d2 = fmaxf(gm + a4.w, 0.0f);
                float dmin = sqrtf(d2);
                float4 b4 = sCand[PADSLOT(bix)];
                vals[0] = (double)dmin;
                vals[1] = (double)a4.x; vals[2] = (double)a4.y; vals[3] = (double)a4.z;
                vals[4] = (double)b4.x; vals[5] = (double)b4.y; vals[6] = (double)b4.z;
                vals[7]  = (double)a4.x*b4.x; vals[8]  = (double)a4.x*b4.y; vals[9]  = (double)a4.x*b4.z;
                vals[10] = (double)a4.y*b4.x; vals[11] = (double)a4.y*b4.y; vals[12] = (double)a4.y*b4.z;
                vals[13] = (double)a4.z*b4.x; vals[14] = (double)a4.z*b4.y; vals[15] = (double)a4.z*b4.z;
            } else {
                #pragma unroll
                for (int k = 0; k < 16; ++k) vals[k] = 0.0;
            }
            #pragma unroll
            for (int off = 1; off < 32; off <<= 1) {
                #pragma unroll
                for (int k = 0; k < 16; ++k) vals[k] += __shfl_xor(vals[k], off, 64);
            }
            if (tid == 0) {
                unsigned long long* dst = bp + (par*NB + bid)*16;
                #pragma unroll
                for (int k = 0; k < 16; ++k) bp_store(&dst[k], vals[k]);
                __hip_atomic_store(&flags[bid], (unsigned)rnd, __ATOMIC_RELEASE, AGENT);
            }
        }
        // ---- wait for all blocks ----
        if (tid < 64) {
            #pragma unroll
            for (int j = 0; j < 4; ++j) {
                while (__hip_atomic_load(&flags[tid*4 + j], __ATOMIC_ACQUIRE, AGENT)
                       < (unsigned)rnd)
                    __builtin_amdgcn_s_sleep(2);
            }
        }
        __syncthreads();

        // ---- redundant reduce (fixed order) + gate + Kabsch ----
        if (tid < 64) {
            double sv[16];
            #pragma unroll
            for (int k = 0; k < 16; ++k) sv[k] = 0.0;
            #pragma unroll
            for (int jj = 0; jj < 4; ++jj) {
                const unsigned long long* row = bp + (par*NB + tid + 64*jj)*16;
                #pragma unroll
                for (int k = 0; k < 16; ++k) sv[k] += bp_load(&row[k]);
            }
            #pragma unroll
            for (int off = 1; off < 64; off <<= 1) {
                #pragma unroll
                for (int k = 0; k < 16; ++k) sv[k] += __shfl_xor(sv[k], off, 64);
            }
            if (tid == 0) {
                double errnew = sv[0] / (double)N_PTS;
                double rel = fabs((errnew - err_loc) / err_loc);  // nan first -> false
                int nd = (rel < TOLV) ? 1 : 0;
                sDone = nd;
                if (!nd) {
                    err_loc = errnew;
                    float c1[3], c2[3], H[3][3], Rm[3][3], tv[3];
                    build_Hf(sv, c1, c2, H);
                    kabsch3f(H, c1, c2, Rm, tv);
                    #pragma unroll
                    for (int i = 0; i < 3; ++i) {
                        sRt[3*i]   = Rm[i][0];
                        sRt[3*i+1] = Rm[i][1];
                        sRt[3*i+2] = Rm[i][2];
                        sRt[9+i]   = tv[i];
                    }
                }
            }
        }
        __syncthreads();
        if (sDone) break;               // frozen from here on: exact ref semantics
        if (tid < QPB) {
            float4 a4 = sQ[tid];
            float x = fmaf(sRt[0], a4.x, fmaf(sRt[1], a4.y, fmaf(sRt[2], a4.z, sRt[9])));
            float y = fmaf(sRt[3], a4.x, fmaf(sRt[4], a4.y, fmaf(sRt[5], a4.z, sRt[10])));
            float z = fmaf(sRt[6], a4.x, fmaf(sRt[7], a4.y, fmaf(sRt[8], a4.z, sRt[11])));
            sQ[tid] = make_float4(x, y, z, x*x + y*y + z*z);
        }
        // loop-top __syncthreads() publishes new sQ before next scan
    }

    // ---- final fit round: a = p1, b = current sQ ----
    ++rnd;
    const int fpar = rnd & 1;
    if (tid < 64) {
        double vals[16];
        if (tid < 32) {
            int q = bid*QPB + tid;
            float ax = p1[3*q], ay = p1[3*q+1], az = p1[3*q+2];
            float4 b4 = sQ[tid];
            vals[0] = 0.0;
            vals[1] = (double)ax;   vals[2] = (double)ay;   vals[3] = (double)az;
            vals[4] = (double)b4.x; vals[5] = (double)b4.y; vals[6] = (double)b4.z;
            vals[7]  = (double)ax*b4.x; vals[8]  = (double)ax*b4.y; vals[9]  = (double)ax*b4.z;
            vals[10] = (double)ay*b4.x; vals[11] = (double)ay*b4.y; vals[12] = (double)ay*b4.z;
            vals[13] = (double)az*b4.x; vals[14] = (double)az*b4.y; vals[15] = (double)az*b4.z;
        } else {
            #pragma unroll
            for (int k = 0; k < 16; ++k) vals[k] = 0.0;
        }
        #pragma unroll
        for (int off = 1; off < 32; off <<= 1) {
            #pragma unroll
            for (int k = 0; k < 16; ++k) vals[k] += __shfl_xor(vals[k], off, 64);
        }
        if (tid == 0) {
            unsigned long long* dst = bp + (fpar*NB + bid)*16;
            #pragma unroll
            for (int k = 0; k < 16; ++k) bp_store(&dst[k], vals[k]);
            __hip_atomic_store(&flags[bid], (unsigned)rnd, __ATOMIC_RELEASE, AGENT);
        }
    }
    if (bid != 0) return;               // only block 0 produces the output

    if (tid < 64) {
        #pragma unroll
        for (int j = 0; j < 4; ++j) {
            while (__hip_atomic_load(&flags[tid*4 + j], __ATOMIC_ACQUIRE, AGENT)
                   < (unsigned)rnd)
                __builtin_amdgcn_s_sleep(2);
        }
        double sv[16];
        #pragma unroll
        for (int k = 0; k < 16; ++k) sv[k] = 0.0;
        #pragma unroll
        for (int jj = 0; jj < 4; ++jj) {
            const unsigned long long* row = bp + (fpar*NB + tid + 64*jj)*16;
            #pragma unroll
            for (int k = 0; k < 16; ++k) sv[k] += bp_load(&row[k]);
        }
        #pragma unroll
        for (int off = 1; off < 64; off <<= 1) {
            #pragma unroll
            for (int k = 0; k < 16; ++k) sv[k] += __shfl_xor(sv[k], off, 64);
        }
        if (tid == 0) {
            float c1[3], c2[3], H[3][3], Rm[3][3], tv[3];
            build_Hf(sv, c1, c2, H);
            kabsch3f(H, c1, c2, Rm, tv);
            #pragma unroll
            for (int i = 0; i < 3; ++i) {
                out[4*i + 0] = Rm[i][0];
                out[4*i + 1] = Rm[i][1];
                out[4*i + 2] = Rm[i][2];
                out[4*i + 3] = tv[i];
            }
        }
    }
}

// ===========================================================================
// FALLBACK: r6 multi-dispatch path (proven 305 us), f32 Kabsch.
// ===========================================================================
__global__ __launch_bounds__(NT, 2) void fb_step(
    const float* __restrict__ p1, const float* __restrict__ p2,
    float4* __restrict__ p2f, float* __restrict__ temppc,
    const double* __restrict__ bp_prev, double* __restrict__ bp_cur,
    double* __restrict__ err_hist, int* __restrict__ done_hist, int it)
{
    __shared__ float4 sCand[SC_SZ];
    __shared__ float4 sQ[QPB];
    __shared__ float  sWB[8][QPT];
    __shared__ int    sWI[8][QPT];
    __shared__ float  sRt[12];
    const int tid = threadIdx.x, bid = blockIdx.x;

    const int latched = (it > 0) ? done_hist[it-1] : 0;
    const bool scanning = (it < NITER);
    if (scanning && latched) {
        if (bid == 0 && tid == 0) { done_hist[it] = 1; err_hist[it] = err_hist[it-1]; }
        return;
    }

    if (scanning) {
        if (it == 0) {
            #pragma unroll
            for (int k = 0; k < 16; ++k) {
                int i = tid + NT*k;
                float x = p2[3*i], y = p2[3*i+1], z = p2[3*i+2];
                sCand[PADSLOT(i)] = make_float4(x, y, z, x*x + y*y + z*z);
            }
        } else {
            #pragma unroll
            for (int k = 0; k < 16; ++k) {
                int i = tid + NT*k;
                sCand[PADSLOT(i)] = p2f[i];
            }
        }
    }

    int done = 0;
    if (it == 0) {
        __syncthreads();
        if (bid == 0 && tid == 0) { err_hist[0] = __builtin_inf(); done_hist[0] = 0; }
        if (tid < QPB) {
            int i = bid*QPB + tid;
            p2f[i] = sCand[PADSLOT(i)];
        }
    } else if (latched) {
        done = 1;   // only reachable when !scanning (final fit after freeze)
    } else {
        __shared__ int sDn;
        if (tid < 64) {
            double sv[16];
            #pragma unroll
            for (int k = 0; k < 16; ++k) sv[k] = 0.0;
            #pragma unroll
            for (int jj = 0; jj < 4; ++jj) {
                const double* row = bp_prev + (tid + 64*jj)*16;
                #pragma unroll
                for (int k = 0; k < 16; ++k) sv[k] += row[k];
            }
            #pragma unroll
            for (int off = 1; off < 64; off <<= 1) {
                #pragma unroll
                for (int k = 0; k < 16; ++k) sv[k] += __shfl_xor(sv[k], off, 64);
            }
            if (tid == 0) {
                double errnew = sv[0] / (double)N_PTS;
                double err = err_hist[it-1];
                double rel = fabs((errnew - err) / err);
                int nd = (rel < TOLV) ? 1 : 0;
                if (bid == 0) { done_hist[it] = nd; err_hist[it] = nd ? err : errnew; }
                sDn = nd;
                if (!nd) {
                    float c1[3], c2[3], H[3][3], Rm[3][3], tv[3];
                    build_Hf(sv, c1, c2, H);
                    kabsch3f(H, c1, c2, Rm, tv);
                    for (int i = 0; i < 3; ++i) {
                        sRt[3*i]   = Rm[i][0];
                        sRt[3*i+1] = Rm[i][1];
                        sRt[3*i+2] = Rm[i][2];
                        sRt[9+i]   = tv[i];
                    }
                }
            }
        }
        __syncthreads();
        done = sDn;
    }

    if (done && scanning) return;

    if (tid < QPB) {
        int q = bid*QPB + tid;
        float x, y, z;
        if (it == 0) {
            x = p1[3*q]; y = p1[3*q+1]; z = p1[3*q+2];
            temppc[3*q] = x; temppc[3*q+1] = y; temppc[3*q+2] = z;
        } else {
            x = temppc[3*q]; y = temppc[3*q+1]; z = temppc[3*q+2];
            if (!done) {
                float nx = fmaf(sRt[0], x, fmaf(sRt[1], y, fmaf(sRt[2], z, sRt[9])));
                float ny = fmaf(sRt[3], x, fmaf(sRt[4], y, fmaf(sRt[5], z, sRt[10])));
                float nz = fmaf(sRt[6], x, fmaf(sRt[7], y, fmaf(sRt[8], z, sRt[11])));
                x = nx; y = ny; z = nz;
                temppc[3*q] = x; temppc[3*q+1] = y; temppc[3*q+2] = z;
            }
        }
        sQ[tid] = make_float4(x, y, z, x*x + y*y + z*z);
    }
    __syncthreads();

    double vals[16];
    if (!scanning) {
        if (tid < 64) {
            if (tid < 32) {
                int q = bid*QPB + tid;
                float ax = p1[3*q], ay = p1[3*q+1], az = p1[3*q+2];
                float4 b4 = sQ[tid];
                vals[0] = 0.0;
                vals[1] = (double)ax;   vals[2] = (double)ay;   vals[3] = (double)az;
                vals[4] = (double)b4.x; vals[5] = (double)b4.y; vals[6] = (double)b4.z;
                vals[7]  = (double)ax*b4.x; vals[8]  = (double)ax*b4.y; vals[9]  = (double)ax*b4.z;
                vals[10] = (double)ay*b4.x; vals[11] = (double)ay*b4.y; vals[12] = (double)ay*b4.z;
                vals[13] = (double)az*b4.x; vals[14] = (double)az*b4.y; vals[15] = (double)az*b4.z;
            } else {
                #pragma unroll
                for (int k = 0; k < 16; ++k) vals[k] = 0.0;
            }
            #pragma unroll
            for (int off = 1; off < 32; off <<= 1) {
                #pragma unroll
                for (int k = 0; k < 16; ++k) vals[k] += __shfl_xor(vals[k], off, 64);
            }
            if (tid == 0) {
                double* d = bp_cur + bid*16;
                #pragma unroll
                for (int k = 0; k < 16; ++k) d[k] = vals[k];
            }
        }
        return;
    }

    // NN scan (index-tracking, r6-proven)
    const int g = tid >> 7;
    const int r = tid & 127;
    float qx[QPT], qy[QPT], qz[QPT];
    #pragma unroll
    for (int k = 0; k < QPT; ++k) {
        float4 a = sQ[QPT*g + k];
        qx[k] = -2.f*a.x; qy[k] = -2.f*a.y; qz[k] = -2.f*a.z;
    }
    float best[QPT]; int bi[QPT];
    #pragma unroll
    for (int k = 0; k < QPT; ++k) { best[k] = FLT_MAX; bi[k] = 0; }
    const int sb = 65*r;
    const int gb = 64*r;
    float4 cur = sCand[sb];
    #pragma unroll 4
    for (int j = 0; j < RC - 1; ++j) {
        float4 nxt = sCand[sb + j + 1];
        #pragma unroll
        for (int k = 0; k < QPT; ++k) {
            float v = dist_val(cur, qx[k], qy[k], qz[k]);
            if (v < best[k]) { best[k] = v; bi[k] = gb + j; }
        }
        cur = nxt;
    }
    #pragma unroll
    for (int k = 0; k < QPT; ++k) {
        float v = dist_val(cur, qx[k], qy[k], qz[k]);
        if (v < best[k]) { best[k] = v; bi[k] = gb + RC - 1; }
    }
    #pragma unroll
    for (int off = 1; off < 64; off <<= 1) {
        #pragma unroll
        for (int k = 0; k < QPT; ++k) {
            float ov = __shfl_xor(best[k], off, 64);
            int   oi = __shfl_xor(bi[k],  off, 64);
            if (ov < best[k] || (ov == best[k] && oi < bi[k])) { best[k] = ov; bi[k] = oi; }
        }
    }
    const int w = tid >> 6;
    if ((tid & 63) == 0) {
        #pragma unroll
        for (int k = 0; k < QPT; ++k) { sWB[w][k] = best[k]; sWI[w][k] = bi[k]; }
    }
    __syncthreads();

    if (tid < 64) {
        if (tid < 32) {
            int q = tid, gg = q >> 3, k2 = q & 7;
            float bv = sWB[2*gg][k2];   int bix = sWI[2*gg][k2];
            float ov = sWB[2*gg+1][k2]; int oi  = sWI[2*gg+1][k2];
            if (ov < bv || (ov == bv && oi < bix)) { bv = ov; bix = oi; }
            float4 a4 = sQ[q];
            float d2 = fmaxf(bv + a4.w, 0.0f);
            float dmin = sqrtf(d2);
            float4 b4 = sCand[PADSLOT(bix)];
            vals[0] = (double)dmin;
            vals[1] = (double)a4.x; vals[2] = (double)a4.y; vals[3] = (double)a4.z;
            vals[4] = (double)b4.x; vals[5] = (double)b4.y; vals[6] = (double)b4.z;
            vals[7]  = (double)a4.x*b4.x; vals[8]  = (double)a4.x*b4.y; vals[9]  = (double)a4.x*b4.z;
            vals[10] = (double)a4.y*b4.x; vals[11] = (double)a4.y*b4.y; vals[12] = (double)a4.y*b4.z;
            vals[13] = (double)a4.z*b4.x; vals[14] = (double)a4.z*b4.y; vals[15] = (double)a4.z*b4.z;
        } else {
            #pragma unroll
            for (int k = 0; k < 16; ++k) vals[k] = 0.0;
        }
        #pragma unroll
        for (int off = 1; off < 32; off <<= 1) {
            #pragma unroll
            for (int k = 0; k < 16; ++k) vals[k] += __shfl_xor(vals[k], off, 64);
        }
        if (tid == 0) {
            double* d = bp_cur + bid*16;
            #pragma unroll
            for (int k = 0; k < 16; ++k) d[k] = vals[k];
        }
    }
}

__global__ void fb_final(const double* __restrict__ bp, float* __restrict__ out) {
    int tid = threadIdx.x;
    double sv[16];
    #pragma unroll
    for (int k = 0; k < 16; ++k) sv[k] = 0.0;
    #pragma unroll
    for (int j = 0; j < 4; ++j) {
        const double* row = bp + (tid + 64*j)*16;
        #pragma unroll
        for (int k = 0; k < 16; ++k) sv[k] += row[k];
    }
    #pragma unroll
    for (int off = 1; off < 64; off <<= 1) {
        #pragma unroll
        for (int k = 0; k < 16; ++k) sv[k] += __shfl_xor(sv[k], off, 64);
    }
    if (tid == 0) {
        float c1[3], c2[3], H[3][3], Rm[3][3], tv[3];
        build_Hf(sv, c1, c2, H);
        kabsch3f(H, c1, c2, Rm, tv);
        for (int i = 0; i < 3; ++i) {
            out[4*i + 0] = Rm[i][0];
            out[4*i + 1] = Rm[i][1];
            out[4*i + 2] = Rm[i][2];
            out[4*i + 3] = tv[i];
        }
    }
}

// ===========================================================================
extern "C" void kernel_launch(void* const* d_in, const int* in_sizes, int n_in,
                              void* d_out, int out_size, void* d_ws, size_t ws_size,
                              hipStream_t stream) {
    const float* p1 = (const float*)d_in[0];
    const float* p2 = (const float*)d_in[1];
    float* out = (float*)d_out;
    char* ws = (char*)d_ws;

    unsigned long long* bp    = (unsigned long long*)(ws + WS_BP);
    unsigned int*       flags = (unsigned int*)      (ws + WS_FLAGS);

    hipMemsetAsync(ws + WS_FLAGS, 0, NB*sizeof(unsigned int), stream);

    void* args[] = { (void*)&p1, (void*)&p2, (void*)&bp, (void*)&flags, (void*)&out };
    hipError_t e = hipLaunchCooperativeKernel((const void*)icp_persist,
                                              dim3(NB), dim3(NT), args, 0, stream);
    if (e != hipSuccess) {
        (void)hipGetLastError();
        float4* p2f       = (float4*)(ws + WS_P2F);
        float*  temppc    = (float*) (ws + WS_TEMPPC);
        double* bpA       = (double*)(ws + WS_FBA);
        double* bpB       = (double*)(ws + WS_FBB);
        double* err_hist  = (double*)(ws + WS_ERRH);
        int*    done_hist = (int*)   (ws + WS_DONEH);
        for (int it = 0; it <= NITER; ++it) {
            double* curb = (it & 1) ? bpB : bpA;
            double* prvb = (it & 1) ? bpA : bpB;
            fb_step<<<NB, NT, 0, stream>>>(p1, p2, p2f, temppc, prvb, curb,
                                           err_hist, done_hist, it);
        }
        fb_final<<<1, 64, 0, stream>>>(bpB, out);   // NITER odd -> last in bpB
    }
}

// Round 9
// 373.303 us; speedup vs baseline: 2.0058x; 1.1303x over previous
//
#include <hip/hip_runtime.h>
#include <float.h>
#include <math.h>

#define N_PTS 8192
#define NB    256         // blocks (1 per CU)
#define NT    512         // 8 waves/block
#define QPB   32          // queries per block
#define QPT   8           // queries per thread group
#define RC    64          // candidates per range
#define STEPS 11          // NN/gate scan iterations (STEPLIM + 1)
#define TOLV  1e-4

#define PADSLOT(i) ((i) + ((i) >> 6))
#define SC_SZ (N_PTS + N_PTS/64)   // 8320 float4 slots = 133120 B

// ---- ws layout (bytes) ----
#define WS_TEMPPC 0        // float [24576]   ->  98304
#define WS_BPA    98304    // double[256*16]  -> 131072
#define WS_BPB    131072   // double[256*16]  -> 163840
#define WS_ERRH   163840   // double[16]      -> 163968
#define WS_DONEH  163968   // int[16]

// ===========================================================================
// f32 Kabsch via Jacobi eigendecomposition of H^T H (reference SVD is f32).
// Proven trajectory-exact in r7/r8 (absmax 0.0).
// ===========================================================================
__device__ void kabsch3f(const float H[3][3], const float c1[3], const float c2[3],
                         float R[3][3], float t[3]) {
    float A[3][3];
    for (int i = 0; i < 3; ++i)
        for (int j = 0; j < 3; ++j) {
            float sacc = 0.0f;
            for (int k = 0; k < 3; ++k) sacc += H[k][i] * H[k][j];
            A[i][j] = sacc;
        }
    float V[3][3] = {{1,0,0},{0,1,0},{0,0,1}};
    for (int sweep = 0; sweep < 6; ++sweep) {
        const int PQ[3][2] = {{0,1},{0,2},{1,2}};
        for (int mm = 0; mm < 3; ++mm) {
            int p = PQ[mm][0], q = PQ[mm][1];
            float apq = A[p][q];
            if (fabsf(apq) < 1e-30f) continue;
            float app = A[p][p], aqq = A[q][q];
            float tau = (aqq - app) / (2.0f * apq);
            float tt = (tau >= 0.0f) ? 1.0f / (tau + sqrtf(1.0f + tau*tau))
                                     : 1.0f / (tau - sqrtf(1.0f + tau*tau));
            float c = 1.0f / sqrtf(1.0f + tt*tt), s = tt * c;
            A[p][p] = app - tt * apq;
            A[q][q] = aqq + tt * apq;
            A[p][q] = 0.0f; A[q][p] = 0.0f;
            int k = 3 - p - q;
            float akp = A[k][p], akq = A[k][q];
            A[k][p] = c*akp - s*akq; A[p][k] = A[k][p];
            A[k][q] = s*akp + c*akq; A[q][k] = A[k][q];
            for (int r = 0; r < 3; ++r) {
                float vp = V[r][p], vq = V[r][q];
                V[r][p] = c*vp - s*vq;
                V[r][q] = s*vp + c*vq;
            }
        }
    }
    float lam[3] = {A[0][0], A[1][1], A[2][2]};
    int ord[3] = {0,1,2};
    for (int i = 0; i < 2; ++i)
        for (int j = i+1; j < 3; ++j)
            if (lam[ord[j]] > lam[ord[i]]) { int tmp = ord[i]; ord[i] = ord[j]; ord[j] = tmp; }
    float v0[3] = {V[0][ord[0]], V[1][ord[0]], V[2][ord[0]]};
    float v1[3] = {V[0][ord[1]], V[1][ord[1]], V[2][ord[1]]};
    float v2[3] = {V[0][ord[2]], V[1][ord[2]], V[2][ord[2]]};

    float u0[3], u1[3], hv2[3];
    for (int i = 0; i < 3; ++i) u0[i] = H[i][0]*v0[0] + H[i][1]*v0[1] + H[i][2]*v0[2];
    float n0 = sqrtf(u0[0]*u0[0] + u0[1]*u0[1] + u0[2]*u0[2]);
    n0 = fmaxf(n0, 1e-30f);
    for (int i = 0; i < 3; ++i) u0[i] /= n0;

    for (int i = 0; i < 3; ++i) u1[i] = H[i][0]*v1[0] + H[i][1]*v1[1] + H[i][2]*v1[2];
    float d01 = u1[0]*u0[0] + u1[1]*u0[1] + u1[2]*u0[2];
    for (int i = 0; i < 3; ++i) u1[i] -= d01 * u0[i];
    float n1 = sqrtf(u1[0]*u1[0] + u1[1]*u1[1] + u1[2]*u1[2]);
    n1 = fmaxf(n1, 1e-30f);
    for (int i = 0; i < 3; ++i) u1[i] /= n1;

    float u2[3] = {u0[1]*u1[2] - u0[2]*u1[1],
                   u0[2]*u1[0] - u0[0]*u1[2],
                   u0[0]*u1[1] - u0[1]*u1[0]};
    for (int i = 0; i < 3; ++i) hv2[i] = H[i][0]*v2[0] + H[i][1]*v2[1] + H[i][2]*v2[2];
    if (hv2[0]*u2[0] + hv2[1]*u2[1] + hv2[2]*u2[2] < 0.0f) {
        v2[0] = -v2[0]; v2[1] = -v2[1]; v2[2] = -v2[2];
    }
    float cx = v1[1]*v2[2] - v1[2]*v2[1];
    float cy = v1[2]*v2[0] - v1[0]*v2[2];
    float cz = v1[0]*v2[1] - v1[1]*v2[0];
    float detV = v0[0]*cx + v0[1]*cy + v0[2]*cz;
    float dsg = (detV < 0.0f) ? -1.0f : 1.0f;

    for (int i = 0; i < 3; ++i)
        for (int j = 0; j < 3; ++j)
            R[i][j] = v0[i]*u0[j] + v1[i]*u1[j] + dsg * v2[i]*u2[j];
    for (int i = 0; i < 3; ++i)
        t[i] = c2[i] - (R[i][0]*c1[0] + R[i][1]*c1[1] + R[i][2]*c1[2]);
}

__device__ __forceinline__ void build_Hf(const double s[16], float c1[3], float c2[3],
                                         float H[3][3]) {
    const double Nn = (double)N_PTS;
    double c1d[3] = {s[1]/Nn, s[2]/Nn, s[3]/Nn};
    double c2d[3] = {s[4]/Nn, s[5]/Nn, s[6]/Nn};
    for (int i = 0; i < 3; ++i) { c1[i] = (float)c1d[i]; c2[i] = (float)c2d[i]; }
    for (int i = 0; i < 3; ++i)
        for (int j = 0; j < 3; ++j)
            H[i][j] = (float)(s[7 + 3*i + j] - Nn * c1d[i] * c2d[j]);
}

// identical fma chain in scan & rescan -> exact float equality in recovery
__device__ __forceinline__ float dist_val(float4 s, float mx, float my, float mz) {
    float v = fmaf(mx, s.x, s.w);
    v = fmaf(my, s.y, v);
    v = fmaf(mz, s.z, v);
    return v;
}

// ===========================================================================
// One ICP iteration per dispatch (it = 0..STEPS-1).
// Wave 0: gate reduce + f32 Kabsch of step it-1 (runs CONCURRENTLY with
// staging by waves 1..7). Then transform own 32 queries + value-only NN scan
// + rescan recovery + per-block covariance partials.
// ===========================================================================
__global__ __launch_bounds__(NT) void icp_scan(
    const float* __restrict__ p1, const float* __restrict__ p2,
    float* __restrict__ temppc,
    const double* __restrict__ bp_prev, double* __restrict__ bp_cur,
    double* __restrict__ err_hist, int* __restrict__ done_hist, int it)
{
    __shared__ float4 sCand[SC_SZ];      // 133120 B
    __shared__ float4 sQ[QPB];
    __shared__ float  sWmin[8][QPT];
    __shared__ int    sWin[QPB];
    __shared__ float  sRt[12];
    __shared__ int    sDone;
    const int tid = threadIdx.x, bid = blockIdx.x;

    // latched: everything frozen; forward the latch and exit
    if (it > 0 && done_hist[it-1]) {
        if (bid == 0 && tid == 0) { done_hist[it] = 1; err_hist[it] = err_hist[it-1]; }
        return;
    }

    if (tid < QPB) sWin[tid] = 0x7fffffff;

    if (it == 0) {
        // all 8 waves stage; no gate yet
        #pragma unroll
        for (int k = 0; k < 16; ++k) {
            int i = tid + NT*k;
            float x = p2[3*i], y = p2[3*i+1], z = p2[3*i+2];
            sCand[PADSLOT(i)] = make_float4(x, y, z, x*x + y*y + z*z);
        }
        if (tid == 0) {
            sDone = 0;
            if (bid == 0) { err_hist[0] = __builtin_inf(); done_hist[0] = 0; }
        }
    } else if (tid >= 64) {
        // waves 1..7: staging (448 threads), overlaps wave 0's gate
        for (int i = tid - 64; i < N_PTS; i += NT - 64) {
            float x = p2[3*i], y = p2[3*i+1], z = p2[3*i+2];
            sCand[PADSLOT(i)] = make_float4(x, y, z, x*x + y*y + z*z);
        }
    } else {
        // wave 0: gate reduce (fixed order -> deterministic) + Kabsch
        double sv[16];
        #pragma unroll
        for (int k = 0; k < 16; ++k) sv[k] = 0.0;
        #pragma unroll
        for (int jj = 0; jj < 4; ++jj) {
            const double* row = bp_prev + (tid + 64*jj)*16;
            #pragma unroll
            for (int k = 0; k < 16; ++k) sv[k] += row[k];
        }
        #pragma unroll
        for (int off = 1; off < 64; off <<= 1) {
            #pragma unroll
            for (int k = 0; k < 16; ++k) sv[k] += __shfl_xor(sv[k], off, 64);
        }
        if (tid == 0) {
            double errnew = sv[0] / (double)N_PTS;
            double err = err_hist[it-1];
            double rel = fabs((errnew - err) / err);   // nan when err=inf -> false
            int nd = (rel < TOLV) ? 1 : 0;
            if (bid == 0) { done_hist[it] = nd; err_hist[it] = nd ? err : errnew; }
            sDone = nd;
            if (!nd) {
                float c1[3], c2[3], H[3][3], Rm[3][3], tv[3];
                build_Hf(sv, c1, c2, H);
                kabsch3f(H, c1, c2, Rm, tv);
                #pragma unroll
                for (int i = 0; i < 3; ++i) {
                    sRt[3*i]   = Rm[i][0];
                    sRt[3*i+1] = Rm[i][1];
                    sRt[3*i+2] = Rm[i][2];
                    sRt[9+i]   = tv[i];
                }
            }
        }
    }
    __syncthreads();
    if (sDone) return;   // fresh convergence: latch already written; freeze

    // ---- own query coords: load, (transform), store, share ----
    if (tid < QPB) {
        int q = bid*QPB + tid;
        float x, y, z;
        if (it == 0) {
            x = p1[3*q]; y = p1[3*q+1]; z = p1[3*q+2];
        } else {
            float ox = temppc[3*q], oy = temppc[3*q+1], oz = temppc[3*q+2];
            x = fmaf(sRt[0], ox, fmaf(sRt[1], oy, fmaf(sRt[2], oz, sRt[9])));
            y = fmaf(sRt[3], ox, fmaf(sRt[4], oy, fmaf(sRt[5], oz, sRt[10])));
            z = fmaf(sRt[6], ox, fmaf(sRt[7], oy, fmaf(sRt[8], oz, sRt[11])));
        }
        temppc[3*q] = x; temppc[3*q+1] = y; temppc[3*q+2] = z;
        sQ[tid] = make_float4(x, y, z, x*x + y*y + z*z);
    }
    __syncthreads();

    // ---- NN scan: group g (8 queries) x range r (64 cands), value-only ----
    const int g = tid >> 7;          // 0..3
    const int r = tid & 127;         // 0..127
    float qx[QPT], qy[QPT], qz[QPT];
    #pragma unroll
    for (int k = 0; k < QPT; ++k) {
        float4 a = sQ[QPT*g + k];
        qx[k] = -2.f*a.x; qy[k] = -2.f*a.y; qz[k] = -2.f*a.z;
    }
    float tmin[QPT];
    #pragma unroll
    for (int k = 0; k < QPT; ++k) tmin[k] = FLT_MAX;
    const int sb = 65*r;             // PADSLOT(64*r): contiguous 64 slots
    float4 cur = sCand[sb];
    #pragma unroll 4
    for (int j = 0; j < RC - 1; ++j) {
        float4 nxt = sCand[sb + j + 1];
        #pragma unroll
        for (int k = 0; k < QPT; ++k)
            tmin[k] = fminf(tmin[k], dist_val(cur, qx[k], qy[k], qz[k]));
        cur = nxt;
    }
    #pragma unroll
    for (int k = 0; k < QPT; ++k)
        tmin[k] = fminf(tmin[k], dist_val(cur, qx[k], qy[k], qz[k]));

    float omin[QPT];                 // per-range minima (pre-butterfly)
    #pragma unroll
    for (int k = 0; k < QPT; ++k) omin[k] = tmin[k];
    #pragma unroll
    for (int off = 1; off < 64; off <<= 1) {
        #pragma unroll
        for (int k = 0; k < QPT; ++k)
            tmin[k] = fminf(tmin[k], __shfl_xor(tmin[k], off, 64));
    }
    const int w = tid >> 6;
    if ((tid & 63) == 0) {
        #pragma unroll
        for (int k = 0; k < QPT; ++k) sWmin[w][k] = tmin[k];
    }
    __syncthreads();

    // winner range per query: smallest r achieving the global min
    #pragma unroll
    for (int k = 0; k < QPT; ++k) {
        float gm = fminf(sWmin[2*g][k], sWmin[2*g+1][k]);
        if (omin[k] == gm) atomicMin(&sWin[QPT*g + k], r);
    }
    __syncthreads();

    // ---- finisher: rescan winning range (first-index) + block partials ----
    if (tid < 64) {
        double vals[16];
        if (tid < 32) {
            int q = tid, g2 = q >> 3, k2 = q & 7;
            float gm = fminf(sWmin[2*g2][k2], sWmin[2*g2+1][k2]);
            int rw = sWin[q];
            float4 a4 = sQ[q];
            float mx = -2.f*a4.x, my = -2.f*a4.y, mz = -2.f*a4.z;
            int bix = -1;
            const int sbw = 65*rw;
            #pragma unroll 8
            for (int j = 0; j < RC; ++j) {
                float v = dist_val(sCand[sbw + j], mx, my, mz);
                if (v == gm && bix < 0) bix = RC*rw + j;
            }
            float d2 = fmaxf(gm + a4.w, 0.0f);
            float dmin = sqrtf(d2);
            float4 b4 = sCand[PADSLOT(bix)];
            vals[0] = (double)dmin;
            vals[1] = (double)a4.x; vals[2] = (double)a4.y; vals[3] = (double)a4.z;
            vals[4] = (double)b4.x; vals[5] = (double)b4.y; vals[6] = (double)b4.z;
            vals[7]  = (double)a4.x*b4.x; vals[8]  = (double)a4.x*b4.y; vals[9]  = (double)a4.x*b4.z;
            vals[10] = (double)a4.y*b4.x; vals[11] = (double)a4.y*b4.y; vals[12] = (double)a4.y*b4.z;
            vals[13] = (double)a4.z*b4.x; vals[14] = (double)a4.z*b4.y; vals[15] = (double)a4.z*b4.z;
        } else {
            #pragma unroll
            for (int k = 0; k < 16; ++k) vals[k] = 0.0;
        }
        #pragma unroll
        for (int off = 1; off < 32; off <<= 1) {
            #pragma unroll
            for (int k = 0; k < 16; ++k) vals[k] += __shfl_xor(vals[k], off, 64);
        }
        if (tid == 0) {
            double* d = bp_cur + bid*16;
            #pragma unroll
            for (int k = 0; k < 16; ++k) d[k] = vals[k];
        }
    }
}

// ===========================================================================
// Fused final dispatch (1 block): gate of step STEPS-1 + (optional) transform
// + whole-cloud final fit + Kabsch -> out.
// ===========================================================================
__global__ __launch_bounds__(NT) void icp_final(
    const float* __restrict__ p1, const float* __restrict__ temppc,
    const double* __restrict__ bp,
    const double* __restrict__ err_hist, const int* __restrict__ done_hist,
    float* __restrict__ out)
{
    __shared__ float  sRt[12];
    __shared__ int    sDone;
    __shared__ double sred[8][16];
    const int tid = threadIdx.x;

    // ---- gate + Kabsch of step STEPS-1 ----
    if (tid < 64) {
        if (done_hist[STEPS-1]) {
            if (tid == 0) sDone = 1;
        } else {
            double sv[16];
            #pragma unroll
            for (int k = 0; k < 16; ++k) sv[k] = 0.0;
            #pragma unroll
            for (int jj = 0; jj < 4; ++jj) {
                const double* row = bp + (tid + 64*jj)*16;
                #pragma unroll
                for (int k = 0; k < 16; ++k) sv[k] += row[k];
            }
            #pragma unroll
            for (int off = 1; off < 64; off <<= 1) {
                #pragma unroll
                for (int k = 0; k < 16; ++k) sv[k] += __shfl_xor(sv[k], off, 64);
            }
            if (tid == 0) {
                double errnew = sv[0] / (double)N_PTS;
                double err = err_hist[STEPS-1];
                double rel = fabs((errnew - err) / err);
                int nd = (rel < TOLV) ? 1 : 0;
                sDone = nd;
                if (!nd) {
                    float c1[3], c2[3], H[3][3], Rm[3][3], tv[3];
                    build_Hf(sv, c1, c2, H);
                    kabsch3f(H, c1, c2, Rm, tv);
                    #pragma unroll
                    for (int i = 0; i < 3; ++i) {
                        sRt[3*i]   = Rm[i][0];
                        sRt[3*i+1] = Rm[i][1];
                        sRt[3*i+2] = Rm[i][2];
                        sRt[9+i]   = tv[i];
                    }
                }
            }
        }
    }
    __syncthreads();
    const int dn = sDone;

    // ---- final fit partial sums: a = p1, b = (transformed) temppc ----
    double acc[16];
    #pragma unroll
    for (int k = 0; k < 16; ++k) acc[k] = 0.0;
    for (int i = tid; i < N_PTS; i += NT) {
        float ax = p1[3*i], ay = p1[3*i+1], az = p1[3*i+2];
        float bx = temppc[3*i], by = temppc[3*i+1], bz = temppc[3*i+2];
        if (!dn) {
            float nx = fmaf(sRt[0], bx, fmaf(sRt[1], by, fmaf(sRt[2], bz, sRt[9])));
            float ny = fmaf(sRt[3], bx, fmaf(sRt[4], by, fmaf(sRt[5], bz, sRt[10])));
            float nz = fmaf(sRt[6], bx, fmaf(sRt[7], by, fmaf(sRt[8], bz, sRt[11])));
            bx = nx; by = ny; bz = nz;
        }
        acc[1] += (double)ax;  acc[2] += (double)ay;  acc[3] += (double)az;
        acc[4] += (double)bx;  acc[5] += (double)by;  acc[6] += (double)bz;
        acc[7]  += (double)ax*bx; acc[8]  += (double)ax*by; acc[9]  += (double)ax*bz;
        acc[10] += (double)ay*bx; acc[11] += (double)ay*by; acc[12] += (double)ay*bz;
        acc[13] += (double)az*bx; acc[14] += (double)az*by; acc[15] += (double)az*bz;
    }
    #pragma unroll
    for (int off = 1; off < 64; off <<= 1) {
        #pragma unroll
        for (int k = 0; k < 16; ++k) acc[k] += __shfl_xor(acc[k], off, 64);
    }
    const int w = tid >> 6;
    if ((tid & 63) == 0) {
        #pragma unroll
        for (int k = 0; k < 16; ++k) sred[w][k] = acc[k];
    }
    __syncthreads();
    if (tid == 0) {
        double sv[16];
        #pragma unroll
        for (int k = 0; k < 16; ++k) {
            double s = 0.0;
            #pragma unroll
            for (int ww = 0; ww < 8; ++ww) s += sred[ww][k];
            sv[k] = s;
        }
        float c1[3], c2[3], H[3][3], Rm[3][3], tv[3];
        build_Hf(sv, c1, c2, H);
        kabsch3f(H, c1, c2, Rm, tv);
        #pragma unroll
        for (int i = 0; i < 3; ++i) {
            out[4*i + 0] = Rm[i][0];
            out[4*i + 1] = Rm[i][1];
            out[4*i + 2] = Rm[i][2];
            out[4*i + 3] = tv[i];
        }
    }
}

// ===========================================================================
extern "C" void kernel_launch(void* const* d_in, const int* in_sizes, int n_in,
                              void* d_out, int out_size, void* d_ws, size_t ws_size,
                              hipStream_t stream) {
    const float* p1 = (const float*)d_in[0];
    const float* p2 = (const float*)d_in[1];
    float* out = (float*)d_out;
    char* ws = (char*)d_ws;

    float*  temppc    = (float*) (ws + WS_TEMPPC);
    double* bpA       = (double*)(ws + WS_BPA);
    double* bpB       = (double*)(ws + WS_BPB);
    double* err_hist  = (double*)(ws + WS_ERRH);
    int*    done_hist = (int*)   (ws + WS_DONEH);

    for (int it = 0; it < STEPS; ++it) {
        double* cur  = (it & 1) ? bpB : bpA;
        double* prev = (it & 1) ? bpA : bpB;
        icp_scan<<<NB, NT, 0, stream>>>(p1, p2, temppc, prev, cur,
                                        err_hist, done_hist, it);
    }
    // STEPS-1 = 10 (even) -> last scan wrote bpA
    icp_final<<<1, NT, 0, stream>>>(p1, temppc, bpA, err_hist, done_hist, out);
}

// Round 10
// 249.300 us; speedup vs baseline: 3.0035x; 1.4974x over previous
//
#include <hip/hip_runtime.h>
#include <float.h>
#include <math.h>

#define N_PTS 8192
#define NB    256         // blocks (1 per CU)
#define NT    1024        // 16 waves/block -> 4 waves/SIMD
#define QPB   32          // queries per block
#define QPT   8           // queries per thread group
#define NRG   256         // candidate ranges
#define RC    32          // candidates per range
#define STEPS 11          // NN/gate scan iterations (STEPLIM + 1)
#define TOLV  1e-4

#define PADSLOT(i) ((i) + ((i) >> 6))
#define SC_SZ (N_PTS + N_PTS/64)   // 8320 float4 slots = 133120 B
// range r (32 cands) lies inside 64-slot pad block r/2:
#define RBASE(r) (65*((r) >> 1) + 32*((r) & 1))

// ---- ws layout (bytes) ----
#define WS_P2F    0        // float4[8192]    -> 131072
#define WS_TEMPPC 131072   // float [24576]   -> 229376
#define WS_BPA    229376   // double[256*16]  -> 262144
#define WS_BPB    262144   // double[256*16]  -> 294912
#define WS_ERRH   294912   // double[16]      -> 295040
#define WS_DONEH  295040   // int[16]

// ===========================================================================
// f32 Kabsch via Jacobi eigendecomposition of H^T H (reference SVD is f32).
// Proven trajectory-exact in r7/r8/r9 (absmax 0.0).
// ===========================================================================
__device__ void kabsch3f(const float H[3][3], const float c1[3], const float c2[3],
                         float R[3][3], float t[3]) {
    float A[3][3];
    for (int i = 0; i < 3; ++i)
        for (int j = 0; j < 3; ++j) {
            float sacc = 0.0f;
            for (int k = 0; k < 3; ++k) sacc += H[k][i] * H[k][j];
            A[i][j] = sacc;
        }
    float V[3][3] = {{1,0,0},{0,1,0},{0,0,1}};
    for (int sweep = 0; sweep < 6; ++sweep) {
        const int PQ[3][2] = {{0,1},{0,2},{1,2}};
        for (int mm = 0; mm < 3; ++mm) {
            int p = PQ[mm][0], q = PQ[mm][1];
            float apq = A[p][q];
            if (fabsf(apq) < 1e-30f) continue;
            float app = A[p][p], aqq = A[q][q];
            float tau = (aqq - app) / (2.0f * apq);
            float tt = (tau >= 0.0f) ? 1.0f / (tau + sqrtf(1.0f + tau*tau))
                                     : 1.0f / (tau - sqrtf(1.0f + tau*tau));
            float c = 1.0f / sqrtf(1.0f + tt*tt), s = tt * c;
            A[p][p] = app - tt * apq;
            A[q][q] = aqq + tt * apq;
            A[p][q] = 0.0f; A[q][p] = 0.0f;
            int k = 3 - p - q;
            float akp = A[k][p], akq = A[k][q];
            A[k][p] = c*akp - s*akq; A[p][k] = A[k][p];
            A[k][q] = s*akp + c*akq; A[q][k] = A[k][q];
            for (int r = 0; r < 3; ++r) {
                float vp = V[r][p], vq = V[r][q];
                V[r][p] = c*vp - s*vq;
                V[r][q] = s*vp + c*vq;
            }
        }
    }
    float lam[3] = {A[0][0], A[1][1], A[2][2]};
    int ord[3] = {0,1,2};
    for (int i = 0; i < 2; ++i)
        for (int j = i+1; j < 3; ++j)
            if (lam[ord[j]] > lam[ord[i]]) { int tmp = ord[i]; ord[i] = ord[j]; ord[j] = tmp; }
    float v0[3] = {V[0][ord[0]], V[1][ord[0]], V[2][ord[0]]};
    float v1[3] = {V[0][ord[1]], V[1][ord[1]], V[2][ord[1]]};
    float v2[3] = {V[0][ord[2]], V[1][ord[2]], V[2][ord[2]]};

    float u0[3], u1[3], hv2[3];
    for (int i = 0; i < 3; ++i) u0[i] = H[i][0]*v0[0] + H[i][1]*v0[1] + H[i][2]*v0[2];
    float n0 = sqrtf(u0[0]*u0[0] + u0[1]*u0[1] + u0[2]*u0[2]);
    n0 = fmaxf(n0, 1e-30f);
    for (int i = 0; i < 3; ++i) u0[i] /= n0;

    for (int i = 0; i < 3; ++i) u1[i] = H[i][0]*v1[0] + H[i][1]*v1[1] + H[i][2]*v1[2];
    float d01 = u1[0]*u0[0] + u1[1]*u0[1] + u1[2]*u0[2];
    for (int i = 0; i < 3; ++i) u1[i] -= d01 * u0[i];
    float n1 = sqrtf(u1[0]*u1[0] + u1[1]*u1[1] + u1[2]*u1[2]);
    n1 = fmaxf(n1, 1e-30f);
    for (int i = 0; i < 3; ++i) u1[i] /= n1;

    float u2[3] = {u0[1]*u1[2] - u0[2]*u1[1],
                   u0[2]*u1[0] - u0[0]*u1[2],
                   u0[0]*u1[1] - u0[1]*u1[0]};
    for (int i = 0; i < 3; ++i) hv2[i] = H[i][0]*v2[0] + H[i][1]*v2[1] + H[i][2]*v2[2];
    if (hv2[0]*u2[0] + hv2[1]*u2[1] + hv2[2]*u2[2] < 0.0f) {
        v2[0] = -v2[0]; v2[1] = -v2[1]; v2[2] = -v2[2];
    }
    float cx = v1[1]*v2[2] - v1[2]*v2[1];
    float cy = v1[2]*v2[0] - v1[0]*v2[2];
    float cz = v1[0]*v2[1] - v1[1]*v2[0];
    float detV = v0[0]*cx + v0[1]*cy + v0[2]*cz;
    float dsg = (detV < 0.0f) ? -1.0f : 1.0f;

    for (int i = 0; i < 3; ++i)
        for (int j = 0; j < 3; ++j)
            R[i][j] = v0[i]*u0[j] + v1[i]*u1[j] + dsg * v2[i]*u2[j];
    for (int i = 0; i < 3; ++i)
        t[i] = c2[i] - (R[i][0]*c1[0] + R[i][1]*c1[1] + R[i][2]*c1[2]);
}

__device__ __forceinline__ void build_Hf(const double s[16], float c1[3], float c2[3],
                                         float H[3][3]) {
    const double Nn = (double)N_PTS;
    double c1d[3] = {s[1]/Nn, s[2]/Nn, s[3]/Nn};
    double c2d[3] = {s[4]/Nn, s[5]/Nn, s[6]/Nn};
    for (int i = 0; i < 3; ++i) { c1[i] = (float)c1d[i]; c2[i] = (float)c2d[i]; }
    for (int i = 0; i < 3; ++i)
        for (int j = 0; j < 3; ++j)
            H[i][j] = (float)(s[7 + 3*i + j] - Nn * c1d[i] * c2d[j]);
}

// identical fma chain in scan & rescan -> exact float equality in recovery
__device__ __forceinline__ float dist_val(float4 s, float mx, float my, float mz) {
    float v = fmaf(mx, s.x, s.w);
    v = fmaf(my, s.y, v);
    v = fmaf(mz, s.z, v);
    return v;
}

// ===========================================================================
// One ICP iteration per dispatch (it = 0..STEPS-1). NT=1024 (4 waves/SIMD).
// Staging: all threads, vectorized float4 (r6-proven). Gate on tid<64 after
// staging issue. Scan: 4 groups (8 q) x 256 ranges (32 cands), value-only,
// rescan recovery (exact first-index argmin).
// ===========================================================================
__global__ __launch_bounds__(NT, 4) void icp_scan(
    const float* __restrict__ p1, const float* __restrict__ p2,
    float4* __restrict__ p2f, float* __restrict__ temppc,
    const double* __restrict__ bp_prev, double* __restrict__ bp_cur,
    double* __restrict__ err_hist, int* __restrict__ done_hist, int it)
{
    __shared__ float4 sCand[SC_SZ];      // 133120 B
    __shared__ float4 sQ[QPB];
    __shared__ float  sWmin[16][QPT];
    __shared__ int    sWin[QPB];
    __shared__ float  sRt[12];
    __shared__ int    sDone;
    const int tid = threadIdx.x, bid = blockIdx.x;

    // latched: everything frozen; forward the latch and exit
    if (it > 0 && done_hist[it-1]) {
        if (bid == 0 && tid == 0) { done_hist[it] = 1; err_hist[it] = err_hist[it-1]; }
        return;
    }

    if (tid < QPB) sWin[tid] = 0x7fffffff;

    // ---- candidate staging: all 1024 threads, 8 slots each, unrolled ----
    if (it == 0) {
        #pragma unroll
        for (int k = 0; k < 8; ++k) {
            int i = tid + NT*k;
            float x = p2[3*i], y = p2[3*i+1], z = p2[3*i+2];
            sCand[PADSLOT(i)] = make_float4(x, y, z, x*x + y*y + z*z);
        }
        if (tid == 0) {
            sDone = 0;
            if (bid == 0) { err_hist[0] = __builtin_inf(); done_hist[0] = 0; }
        }
    } else {
        #pragma unroll
        for (int k = 0; k < 8; ++k) {
            int i = tid + NT*k;
            sCand[PADSLOT(i)] = p2f[i];
        }
        // gate reduce (fixed order -> deterministic) + f32 Kabsch, tid<64
        if (tid < 64) {
            double sv[16];
            #pragma unroll
            for (int k = 0; k < 16; ++k) sv[k] = 0.0;
            #pragma unroll
            for (int jj = 0; jj < 4; ++jj) {
                const double* row = bp_prev + (tid + 64*jj)*16;
                #pragma unroll
                for (int k = 0; k < 16; ++k) sv[k] += row[k];
            }
            #pragma unroll
            for (int off = 1; off < 64; off <<= 1) {
                #pragma unroll
                for (int k = 0; k < 16; ++k) sv[k] += __shfl_xor(sv[k], off, 64);
            }
            if (tid == 0) {
                double errnew = sv[0] / (double)N_PTS;
                double err = err_hist[it-1];
                double rel = fabs((errnew - err) / err);   // nan when err=inf -> false
                int nd = (rel < TOLV) ? 1 : 0;
                if (bid == 0) { done_hist[it] = nd; err_hist[it] = nd ? err : errnew; }
                sDone = nd;
                if (!nd) {
                    float c1[3], c2[3], H[3][3], Rm[3][3], tv[3];
                    build_Hf(sv, c1, c2, H);
                    kabsch3f(H, c1, c2, Rm, tv);
                    #pragma unroll
                    for (int i = 0; i < 3; ++i) {
                        sRt[3*i]   = Rm[i][0];
                        sRt[3*i+1] = Rm[i][1];
                        sRt[3*i+2] = Rm[i][2];
                        sRt[9+i]   = tv[i];
                    }
                }
            }
        }
    }
    __syncthreads();
    if (it > 0 && sDone) return;   // fresh convergence: latch written; freeze

    // publish packed candidates once (block 0 only)
    if (it == 0 && bid == 0) {
        #pragma unroll
        for (int k = 0; k < 8; ++k) {
            int i = tid + NT*k;
            p2f[i] = sCand[PADSLOT(i)];
        }
    }

    // ---- own query coords: load, (transform), store, share ----
    if (tid < QPB) {
        int q = bid*QPB + tid;
        float x, y, z;
        if (it == 0) {
            x = p1[3*q]; y = p1[3*q+1]; z = p1[3*q+2];
        } else {
            float ox = temppc[3*q], oy = temppc[3*q+1], oz = temppc[3*q+2];
            x = fmaf(sRt[0], ox, fmaf(sRt[1], oy, fmaf(sRt[2], oz, sRt[9])));
            y = fmaf(sRt[3], ox, fmaf(sRt[4], oy, fmaf(sRt[5], oz, sRt[10])));
            z = fmaf(sRt[6], ox, fmaf(sRt[7], oy, fmaf(sRt[8], oz, sRt[11])));
        }
        temppc[3*q] = x; temppc[3*q+1] = y; temppc[3*q+2] = z;
        sQ[tid] = make_float4(x, y, z, x*x + y*y + z*z);
    }
    __syncthreads();

    // ---- NN scan: group g (8 queries) x range r (32 cands), value-only ----
    const int g = tid >> 8;          // 0..3
    const int r = tid & 255;         // 0..255
    float qx[QPT], qy[QPT], qz[QPT];
    #pragma unroll
    for (int k = 0; k < QPT; ++k) {
        float4 a = sQ[QPT*g + k];
        qx[k] = -2.f*a.x; qy[k] = -2.f*a.y; qz[k] = -2.f*a.z;
    }
    float tmin[QPT];
    #pragma unroll
    for (int k = 0; k < QPT; ++k) tmin[k] = FLT_MAX;
    const int sb = RBASE(r);         // contiguous 32 slots
    float4 cur = sCand[sb];
    #pragma unroll 4
    for (int j = 0; j < RC - 1; ++j) {
        float4 nxt = sCand[sb + j + 1];
        #pragma unroll
        for (int k = 0; k < QPT; ++k)
            tmin[k] = fminf(tmin[k], dist_val(cur, qx[k], qy[k], qz[k]));
        cur = nxt;
    }
    #pragma unroll
    for (int k = 0; k < QPT; ++k)
        tmin[k] = fminf(tmin[k], dist_val(cur, qx[k], qy[k], qz[k]));

    float omin[QPT];                 // per-range minima (pre-butterfly)
    #pragma unroll
    for (int k = 0; k < QPT; ++k) omin[k] = tmin[k];
    #pragma unroll
    for (int off = 1; off < 64; off <<= 1) {
        #pragma unroll
        for (int k = 0; k < QPT; ++k)
            tmin[k] = fminf(tmin[k], __shfl_xor(tmin[k], off, 64));
    }
    const int w = tid >> 6;          // wave 0..15; group g = w>>2
    if ((tid & 63) == 0) {
        #pragma unroll
        for (int k = 0; k < QPT; ++k) sWmin[w][k] = tmin[k];
    }
    __syncthreads();

    // winner range per query: smallest r achieving the global min
    #pragma unroll
    for (int k = 0; k < QPT; ++k) {
        float gm = fminf(fminf(sWmin[4*g][k],   sWmin[4*g+1][k]),
                         fminf(sWmin[4*g+2][k], sWmin[4*g+3][k]));
        if (omin[k] == gm) atomicMin(&sWin[QPT*g + k], r);
    }
    __syncthreads();

    // ---- finisher: rescan winning range (first-index) + block partials ----
    if (tid < 64) {
        double vals[16];
        if (tid < 32) {
            int q = tid, g2 = q >> 3, k2 = q & 7;
            float gm = fminf(fminf(sWmin[4*g2][k2],   sWmin[4*g2+1][k2]),
                             fminf(sWmin[4*g2+2][k2], sWmin[4*g2+3][k2]));
            int rw = sWin[q];
            float4 a4 = sQ[q];
            float mx = -2.f*a4.x, my = -2.f*a4.y, mz = -2.f*a4.z;
            int bix = -1;
            const int sbw = RBASE(rw);
            #pragma unroll 8
            for (int j = 0; j < RC; ++j) {
                float v = dist_val(sCand[sbw + j], mx, my, mz);
                if (v == gm && bix < 0) bix = RC*rw + j;
            }
            float d2 = fmaxf(gm + a4.w, 0.0f);
            float dmin = sqrtf(d2);
            float4 b4 = sCand[PADSLOT(bix)];
            vals[0] = (double)dmin;
            vals[1] = (double)a4.x; vals[2] = (double)a4.y; vals[3] = (double)a4.z;
            vals[4] = (double)b4.x; vals[5] = (double)b4.y; vals[6] = (double)b4.z;
            vals[7]  = (double)a4.x*b4.x; vals[8]  = (double)a4.x*b4.y; vals[9]  = (double)a4.x*b4.z;
            vals[10] = (double)a4.y*b4.x; vals[11] = (double)a4.y*b4.y; vals[12] = (double)a4.y*b4.z;
            vals[13] = (double)a4.z*b4.x; vals[14] = (double)a4.z*b4.y; vals[15] = (double)a4.z*b4.z;
        } else {
            #pragma unroll
            for (int k = 0; k < 16; ++k) vals[k] = 0.0;
        }
        #pragma unroll
        for (int off = 1; off < 32; off <<= 1) {
            #pragma unroll
            for (int k = 0; k < 16; ++k) vals[k] += __shfl_xor(vals[k], off, 64);
        }
        if (tid == 0) {
            double* d = bp_cur + bid*16;
            #pragma unroll
            for (int k = 0; k < 16; ++k) d[k] = vals[k];
        }
    }
}

// ===========================================================================
// Fused final dispatch (1 block): gate of step STEPS-1 + (optional) transform
// + whole-cloud final fit + Kabsch -> out. (r9-proven)
// ===========================================================================
#define FNT 512
__global__ __launch_bounds__(FNT) void icp_final(
    const float* __restrict__ p1, const float* __restrict__ temppc,
    const double* __restrict__ bp,
    const double* __restrict__ err_hist, const int* __restrict__ done_hist,
    float* __restrict__ out)
{
    __shared__ float  sRt[12];
    __shared__ int    sDone;
    __shared__ double sred[8][16];
    const int tid = threadIdx.x;

    if (tid < 64) {
        if (done_hist[STEPS-1]) {
            if (tid == 0) sDone = 1;
        } else {
            double sv[16];
            #pragma unroll
            for (int k = 0; k < 16; ++k) sv[k] = 0.0;
            #pragma unroll
            for (int jj = 0; jj < 4; ++jj) {
                const double* row = bp + (tid + 64*jj)*16;
                #pragma unroll
                for (int k = 0; k < 16; ++k) sv[k] += row[k];
            }
            #pragma unroll
            for (int off = 1; off < 64; off <<= 1) {
                #pragma unroll
                for (int k = 0; k < 16; ++k) sv[k] += __shfl_xor(sv[k], off, 64);
            }
            if (tid == 0) {
                double errnew = sv[0] / (double)N_PTS;
                double err = err_hist[STEPS-1];
                double rel = fabs((errnew - err) / err);
                int nd = (rel < TOLV) ? 1 : 0;
                sDone = nd;
                if (!nd) {
                    float c1[3], c2[3], H[3][3], Rm[3][3], tv[3];
                    build_Hf(sv, c1, c2, H);
                    kabsch3f(H, c1, c2, Rm, tv);
                    #pragma unroll
                    for (int i = 0; i < 3; ++i) {
                        sRt[3*i]   = Rm[i][0];
                        sRt[3*i+1] = Rm[i][1];
                        sRt[3*i+2] = Rm[i][2];
                        sRt[9+i]   = tv[i];
                    }
                }
            }
        }
    }
    __syncthreads();
    const int dn = sDone;

    double acc[16];
    #pragma unroll
    for (int k = 0; k < 16; ++k) acc[k] = 0.0;
    for (int i = tid; i < N_PTS; i += FNT) {
        float ax = p1[3*i], ay = p1[3*i+1], az = p1[3*i+2];
        float bx = temppc[3*i], by = temppc[3*i+1], bz = temppc[3*i+2];
        if (!dn) {
            float nx = fmaf(sRt[0], bx, fmaf(sRt[1], by, fmaf(sRt[2], bz, sRt[9])));
            float ny = fmaf(sRt[3], bx, fmaf(sRt[4], by, fmaf(sRt[5], bz, sRt[10])));
            float nz = fmaf(sRt[6], bx, fmaf(sRt[7], by, fmaf(sRt[8], bz, sRt[11])));
            bx = nx; by = ny; bz = nz;
        }
        acc[1] += (double)ax;  acc[2] += (double)ay;  acc[3] += (double)az;
        acc[4] += (double)bx;  acc[5] += (double)by;  acc[6] += (double)bz;
        acc[7]  += (double)ax*bx; acc[8]  += (double)ax*by; acc[9]  += (double)ax*bz;
        acc[10] += (double)ay*bx; acc[11] += (double)ay*by; acc[12] += (double)ay*bz;
        acc[13] += (double)az*bx; acc[14] += (double)az*by; acc[15] += (double)az*bz;
    }
    #pragma unroll
    for (int off = 1; off < 64; off <<= 1) {
        #pragma unroll
        for (int k = 0; k < 16; ++k) acc[k] += __shfl_xor(acc[k], off, 64);
    }
    const int w = tid >> 6;
    if ((tid & 63) == 0) {
        #pragma unroll
        for (int k = 0; k < 16; ++k) sred[w][k] = acc[k];
    }
    __syncthreads();
    if (tid == 0) {
        double sv[16];
        #pragma unroll
        for (int k = 0; k < 16; ++k) {
            double s = 0.0;
            #pragma unroll
            for (int ww = 0; ww < 8; ++ww) s += sred[ww][k];
            sv[k] = s;
        }
        float c1[3], c2[3], H[3][3], Rm[3][3], tv[3];
        build_Hf(sv, c1, c2, H);
        kabsch3f(H, c1, c2, Rm, tv);
        #pragma unroll
        for (int i = 0; i < 3; ++i) {
            out[4*i + 0] = Rm[i][0];
            out[4*i + 1] = Rm[i][1];
            out[4*i + 2] = Rm[i][2];
            out[4*i + 3] = tv[i];
        }
    }
}

// ===========================================================================
extern "C" void kernel_launch(void* const* d_in, const int* in_sizes, int n_in,
                              void* d_out, int out_size, void* d_ws, size_t ws_size,
                              hipStream_t stream) {
    const float* p1 = (const float*)d_in[0];
    const float* p2 = (const float*)d_in[1];
    float* out = (float*)d_out;
    char* ws = (char*)d_ws;

    float4* p2f       = (float4*)(ws + WS_P2F);
    float*  temppc    = (float*) (ws + WS_TEMPPC);
    double* bpA       = (double*)(ws + WS_BPA);
    double* bpB       = (double*)(ws + WS_BPB);
    double* err_hist  = (double*)(ws + WS_ERRH);
    int*    done_hist = (int*)   (ws + WS_DONEH);

    for (int it = 0; it < STEPS; ++it) {
        double* cur  = (it & 1) ? bpB : bpA;
        double* prev = (it & 1) ? bpA : bpB;
        icp_scan<<<NB, NT, 0, stream>>>(p1, p2, p2f, temppc, prev, cur,
                                        err_hist, done_hist, it);
    }
    // STEPS-1 = 10 (even) -> last scan wrote bpA
    icp_final<<<1, FNT, 0, stream>>>(p1, temppc, bpA, err_hist, done_hist, out);
}